// Round 1
// 594.105 us; speedup vs baseline: 1.0155x; 1.0155x over previous
//
#include <hip/hip_runtime.h>

// IIR2DResidual: separable bidirectional first-order IIR (a = 0.5, mirror border)
// along W then H on (N=4, H=512, W=512, C=64) fp32 channels-last, then
// out = x + sigmoid(alpha[c]) * (y - x).
//
// R2 change (theory: 4 B/lane scalar global access halves HBM rate, G13):
// re-map lanes so EVERY global access is a 16 B/lane dwordx4.
//   lane l = channels 4*(l&15)..+3 of scan-line (l>>4)  (4 lines per wave)
// The IIR carry is a float4 and stays lane-local; structure otherwise identical
// to the previous (verified) chunked-scan kernel.
//
// Chunking: T=32 outputs, K=8 warm-up halo (0.5^8 ~ 4e-3, mix=0.5 halves it;
// bench threshold 6.6e-2, previous absmax 7.8e-3). WIN=48 float4 = 192 VGPRs;
// __launch_bounds__(256,2) caps allocation at 256 VGPR -> no spill, 2 waves/EU.
//
// Boundary exactness unchanged: mirror init c0 = x[0] exact at w0=0 (warm-up
// steps predicated off); right edge holds yf[L-1] as fixpoint so the
// unconditional backward warm-up is exact.
//
// ws robustness: process images in groups sized to fit ws; if ws can't hold
// one image (64 MiB), fall back to in-place V-pass (no scratch).

typedef float f4 __attribute__((ext_vector_type(4)));

constexpr int Tc   = 32;            // output chunk per wave
constexpr int Kc   = 8;             // warm-up halo
constexpr int WIN  = Tc + 2 * Kc;   // 48 float4 regs/lane
constexpr int L    = 512;           // scan length (H == W == 512)
constexpr int C    = 64;
constexpr int W    = 512;
constexpr int H    = 512;
constexpr int CHUNKS = L / Tc;      // 16

template<bool VERT, bool COMBINE>
__global__ __launch_bounds__(256, 2)
void iir_scan(const float* __restrict__ in, float* __restrict__ out,
              const float* __restrict__ xres, const float* __restrict__ alpha)
{
    const int lane = threadIdx.x & 63;
    const int sub  = lane >> 4;          // which of 4 lines this lane serves
    const int c0   = (lane & 15) << 2;   // channel quad
    const int gw   = blockIdx.x * 4 + (threadIdx.x >> 6);  // wave id
    const int lg   = gw >> 4;            // line-group (4 lines), CHUNKS=16
    const int w0   = (gw & (CHUNKS - 1)) * Tc;

    const int n  = lg >> 7;              // image index within this launch group
    const int r4 = ((lg & 127) << 2) + sub;

    int base, stride;
    if (VERT) {
        // r4 = w; scan over h. One load instr = 16 lanes x 4 sub-w
        //  -> 1 KiB fully contiguous.
        base   = (n * H * W + r4) * C + c0;
        stride = W * C;                  // 128 KiB between scan positions
    } else {
        // r4 = h; scan over w. One load instr = 4 x 256 B dense segments.
        base   = (n * H + r4) * (W * C) + c0;
        stride = C;
    }
    const float* __restrict__ p = in + base;

    f4 v[WIN];
    // --- load window (edge-clamped), 16 B/lane ---
#pragma unroll
    for (int j = 0; j < WIN; ++j) {
        int w = w0 - Kc + j;
        w = min(max(w, 0), L - 1);
        v[j] = *(const f4*)(p + w * stride);
    }

    // --- forward scan: yf[t] = 0.5*x[t] + 0.5*yf[t-1], mirror init ---
    f4 carry = v[0];                     // = x[0] when w0 == 0 (exact mirror)
#pragma unroll
    for (int j = 0; j < WIN; ++j) {
        const int w = w0 - Kc + j;
        if (w >= 0 && w < L)             // wave-uniform predicate
            carry = 0.5f * v[j] + 0.5f * carry;
        v[j] = carry;                    // w >= L: hold yf[L-1] (fixpoint)
    }

    // --- backward scan: yb[t] = 0.5*yf[t] + 0.5*yb[t+1] ---
    f4 c2 = v[WIN - 1];
#pragma unroll
    for (int j = WIN - 1; j >= Kc; --j) {
        c2 = 0.5f * v[j] + 0.5f * c2;
        v[j] = c2;
    }

    // --- store output region [w0, w0+Tc), 16 B/lane ---
    if (COMBINE) {
        const f4 av = *(const f4*)(alpha + c0);
        f4 mix;
#pragma unroll
        for (int q = 0; q < 4; ++q)
            mix[q] = 1.0f / (1.0f + __expf(-av[q]));
#pragma unroll
        for (int j = Kc; j < Kc + Tc; ++j) {
            const int idx = base + (w0 + (j - Kc)) * stride;
            const f4 xv = *(const f4*)(xres + idx);
            *(f4*)(out + idx) = xv + mix * (v[j] - xv);
        }
    } else {
#pragma unroll
        for (int j = Kc; j < Kc + Tc; ++j) {
            const int idx = base + (w0 + (j - Kc)) * stride;
            *(f4*)(out + idx) = v[j];
        }
    }
}

// Emergency V-pass when ws can't hold even one image: in-place on y (the
// H-pass result already in d_out). One wave owns 4 (n,w) lines x 16 channel
// quads -> reads/writes only its own indices, race-free, zero scratch.
__global__ __launch_bounds__(256)
void iir_vpass_inplace(float* __restrict__ y, const float* __restrict__ xres,
                       const float* __restrict__ alpha)
{
    const int lane = threadIdx.x & 63;
    const int sub  = lane >> 4;
    const int c0   = (lane & 15) << 2;
    const int lg   = blockIdx.x * 4 + (threadIdx.x >> 6);  // [0, N*W/4)
    const int n = lg >> 7;
    const int w = ((lg & 127) << 2) + sub;
    const int base   = (n * H * W + w) * C + c0;
    const int stride = W * C;

    // forward, in place
    f4 carry = *(const f4*)(y + base);   // mirror init
    for (int h = 0; h < H; ++h) {
        const int idx = base + h * stride;
        f4 cur = *(const f4*)(y + idx);
        carry = 0.5f * cur + 0.5f * carry;
        *(f4*)(y + idx) = carry;
    }
    // backward + residual, in place
    const f4 av = *(const f4*)(alpha + c0);
    f4 mix;
#pragma unroll
    for (int q = 0; q < 4; ++q)
        mix[q] = 1.0f / (1.0f + __expf(-av[q]));
    f4 c2 = *(const f4*)(y + base + (H - 1) * stride);
    for (int h = H - 1; h >= 0; --h) {
        const int idx = base + h * stride;
        f4 cur = *(const f4*)(y + idx);
        c2 = 0.5f * cur + 0.5f * c2;
        const f4 xv = *(const f4*)(xres + idx);
        *(f4*)(y + idx) = xv + mix * (c2 - xv);
    }
}

extern "C" void kernel_launch(void* const* d_in, const int* in_sizes, int n_in,
                              void* d_out, int out_size, void* d_ws, size_t ws_size,
                              hipStream_t stream) {
    const float* x     = (const float*)d_in[0];
    const float* alpha = (const float*)d_in[1];
    float* out = (float*)d_out;
    float* t   = (float*)d_ws;

    const size_t imgElems = (size_t)H * W * C;          // 16,777,216
    const size_t imgBytes = imgElems * sizeof(float);   // 64 MiB
    const int    N        = 4;

    int g = (int)(ws_size / imgBytes);   // images that fit in ws
    if (g > N) g = N;

    if (g >= 1) {
        // Process images in groups of g: H-pass (x->ws), V-pass+combine (ws->out).
        for (int i0 = 0; i0 < N; i0 += g) {
            const int ni = (i0 + g <= N) ? g : (N - i0);
            const size_t off = (size_t)i0 * imgElems;
            // waves = ni*(H/4) line-groups * 16 chunks; 4 waves/block
            const dim3 grid((unsigned)(ni * 512)), block(256);
            iir_scan<false, false><<<grid, block, 0, stream>>>(x + off, t, nullptr, nullptr);
            iir_scan<true,  true ><<<grid, block, 0, stream>>>(t, out + off, x + off, alpha);
        }
    } else {
        // No usable scratch: H-pass x -> out, then in-place streaming V-pass.
        const dim3 block(256);
        iir_scan<false, false><<<dim3(4 * 512), block, 0, stream>>>(x, out, nullptr, nullptr);
        iir_vpass_inplace<<<dim3(128), block, 0, stream>>>(out, x, alpha);
    }
}